// Round 11
// baseline (84.980 us; speedup 1.0000x reference)
//
#include <hip/hip_runtime.h>

// Fused KernelWarehouse dynamic conv, round 8 (base: R10, 82.2us):
//   logits = 1x1 conv -> softmax K=4 -> 3x3 convs -> mixture (dot2 f16 path).
// R10 post-mortem: dur ~= VALU demand + HBM demand (additive) -> no overlap
// across barriers. Suspect: hipcc's conservative `s_waitcnt vmcnt(0)` before
// s_barrier drains the 2-deep prefetch every iteration (m97 stall; T4/m218:
// counted-vmcnt vs drain0 = +38-73%).
// R11 changes:
//  (1) barrier = asm "s_waitcnt lgkmcnt(0); s_barrier" (NO vmcnt drain --
//      register-dest global loads legally stay in flight across it).
//  (2) iter order: {rv ds_reads; store g+1 (vmcnt wait); issue g+3; compute}.
//  (3) LDSS=44 -> aligned b128 center read + 2 b32 halo reads (18->9 LDS
//      reads/iter); uint4 LDS writes (b128, 16B aligned).
// Kept: 32x32 tile, XCD swizzle (row-mates share fid mod 8), dot2/half2
// channel pairs, LDS double-buffer, 2-deep register prefetch.

typedef _Float16 half2_t __attribute__((ext_vector_type(2)));
typedef unsigned int uint;

#define HH 256
#define WW 256
#define CH 64
#define PLANE (HH * WW)
#define TILE 32
#define NG 32                    // channel pairs (= groups)
#define ROWS 34                  // tile rows incl. halo
#define NC4 10                   // 4-dword units per row ([w0-4, w0+36))
#define LDSS 44                  // dword row stride (mult of 4 -> aligned b128)
#define BUF_DW (ROWS * LDSS)     // 1496 dwords per buffer
#define TU (ROWS * NC4)          // 340 units per group (unit = 4 px x 2 ch)
#define NS 2                     // units per thread (ceil 340/256)

// packed-weight table in d_ws:
//   uint wpk[4][32][9] : half2(w[k][2p][tap], w[k][2p+1][tap])  (1152)
//   uint apk[4][32]    : half2(attn_w[k][2p], attn_w[k][2p+1])  (128)
#define WPK_N 1152
#define APK_OFF 1152

__device__ __forceinline__ uint pkrtz(float a, float b) {
    return __builtin_bit_cast(uint, __builtin_amdgcn_cvt_pkrtz(a, b));
}

__device__ __forceinline__ float dot2(uint a, uint b, float c) {
#if __has_builtin(__builtin_amdgcn_fdot2)
    return __builtin_amdgcn_fdot2(__builtin_bit_cast(half2_t, a),
                                  __builtin_bit_cast(half2_t, b), c, false);
#else
    half2_t ha = __builtin_bit_cast(half2_t, a);
    half2_t hb = __builtin_bit_cast(half2_t, b);
    return c + (float)ha[0] * (float)hb[0] + (float)ha[1] * (float)hb[1];
#endif
}

// workgroup barrier WITHOUT vmcnt drain: LDS ops must be complete (lgkmcnt),
// but outstanding register-dest global loads stay in flight across it.
__device__ __forceinline__ void barrier_lgkm_only() {
    asm volatile("s_waitcnt lgkmcnt(0)\n\ts_barrier" ::: "memory");
}

__global__ void kwdc_pack(const float* __restrict__ weight,
                          const float* __restrict__ attn_w,
                          uint* __restrict__ wsu) {
    int e = blockIdx.x * 256 + threadIdx.x;
    if (e < WPK_N) {
        int k = e / 288, rem = e % 288, pair = rem / 9, tap = rem % 9;
        int c0 = 2 * pair;
        wsu[e] = pkrtz(weight[(k * CH + c0) * 9 + tap],
                       weight[(k * CH + c0 + 1) * 9 + tap]);
    } else if (e < WPK_N + 128) {
        int e2 = e - WPK_N;
        int k = e2 / 32, pair = e2 % 32;
        int c0 = 2 * pair;
        wsu[APK_OFF + e2] = pkrtz(attn_w[k * CH + c0], attn_w[k * CH + c0 + 1]);
    }
}

__global__ __launch_bounds__(256, 4) void kwdc_main(
    const float* __restrict__ x,       // [B,C,H,W] f32
    const uint*  __restrict__ wsu,     // packed weights (d_ws)
    const float* __restrict__ attn_b,  // [K] f32
    float* __restrict__ out)           // [B,1,H,W] f32
{
    __shared__ __align__(16) uint lds[2][BUF_DW];   // 2 x 5.98 KB

    const int tid = threadIdx.x;

    // XCD-aware decode: the 8 tiles of an image row share fid mod 8 -> same XCD
    const int fid = blockIdx.x;        // 0..1023
    const int tw = (fid >> 3) & 7;
    const int th = fid & 7;
    const int b  = fid >> 6;

    const int r  = tid >> 3;     // 0..31 row in tile
    const int cg = tid & 7;      // col group
    const int wb = cg * 4;       // col base (4-wide strip)

    const int h0 = th * TILE;
    const int w0 = tw * TILE;

    const float* xb = x + (size_t)b * CH * PLANE;

    // ---- staging metadata (unit = 4 px of channels 2g, 2g+1) ----
    int  s_gofs[NS];
    int  s_lofs[NS];
    bool s_val[NS];
    bool s_act[NS];
#pragma unroll
    for (int s = 0; s < NS; ++s) {
        int i = tid + s * 256;
        bool act = i < TU;
        int col4 = i % NC4;
        int row  = i / NC4;
        int gh  = h0 + row - 1;
        int gw0 = w0 - 4 + col4 * 4;      // 16B-aligned; fully in or fully out
        s_act[s]  = act;
        s_val[s]  = act && ((unsigned)gh < HH) && ((unsigned)gw0 < WW);
        s_gofs[s] = gh * WW + gw0;
        s_lofs[s] = row * LDSS + col4 * 4;   // 16B aligned (LDSS mult of 4)
    }

    struct Unit { float4 a, b; };
    Unit stgA[NS], stgB[NS];           // 2-deep prefetch sets

    auto load_set = [&](int g, Unit* stg) {
#pragma unroll
        for (int s = 0; s < NS; ++s) {
            float4 va = {0.f, 0.f, 0.f, 0.f}, vb = va;
            if (s_val[s]) {
                const float* pa = xb + (size_t)(2 * g) * PLANE + s_gofs[s];
                va = *reinterpret_cast<const float4*>(pa);
                vb = *reinterpret_cast<const float4*>(pa + PLANE);
            }
            stg[s].a = va; stg[s].b = vb;
        }
    };

    auto store_set = [&](const Unit* stg, int buf) {
#pragma unroll
        for (int s = 0; s < NS; ++s) {
            if (s_act[s]) {
                uint4 q;
                q.x = pkrtz(stg[s].a.x, stg[s].b.x);
                q.y = pkrtz(stg[s].a.y, stg[s].b.y);
                q.z = pkrtz(stg[s].a.z, stg[s].b.z);
                q.w = pkrtz(stg[s].a.w, stg[s].b.w);
                *reinterpret_cast<uint4*>(&lds[buf][s_lofs[s]]) = q;  // b128
            }
        }
    };

    float conv[4][4];
    float logit[4][4];
#pragma unroll
    for (int k = 0; k < 4; ++k)
#pragma unroll
        for (int p = 0; p < 4; ++p) { conv[k][p] = 0.f; logit[k][p] = 0.f; }

    // ---- prologue: stage pair 0; prime 2-deep pipeline ----
    load_set(0, stgA);
    store_set(stgA, 0);
    load_set(1, stgA);   // A holds g1 (stored at iter 0)
    load_set(2, stgB);   // B holds g2 (stored at iter 1)
    barrier_lgkm_only(); // buf0 ready; g1/g2 loads remain in flight

    for (int g = 0; g < NG; ++g) {
        // ---- LDS reads first: aligned b128 center + 2 b32 halo per row ----
        // lds dword j (in row) <-> global col w0-4+j ; thread needs cols
        // wb-1..wb+4 -> j = wb+3..wb+8 ; tp4 at j=wb+4 is 16B aligned.
        const uint* rowp = &lds[g & 1][r * LDSS + wb + 4];
        uint rv[3][6];
#pragma unroll
        for (int i = 0; i < 3; ++i) {
            const uint* tp4 = rowp + i * LDSS;
            uint4 c4 = *reinterpret_cast<const uint4*>(tp4);
            rv[i][0] = tp4[-1];
            rv[i][1] = c4.x; rv[i][2] = c4.y; rv[i][3] = c4.z; rv[i][4] = c4.w;
            rv[i][5] = tp4[4];
        }

        // ---- store set (holds g+1, loaded 2 iters ago); refill with g+3 ----
        if (g + 1 < NG) {
            Unit* setp = (g & 1) ? stgB : stgA;
            store_set(setp, (g + 1) & 1);
            if (g + 3 < NG) load_set(g + 3, setp);
        }

        // ---- packed weights for this pair (uniform -> s_load) ----
        uint w2[4][9];
        uint a2[4];
#pragma unroll
        for (int k = 0; k < 4; ++k) {
            const uint* wq = wsu + k * 288 + g * 9;
#pragma unroll
            for (int t = 0; t < 9; ++t) w2[k][t] = wq[t];
            a2[k] = wsu[APK_OFF + k * 32 + g];
        }

        // ---- compute both channels of the pair via dot2 ----
#pragma unroll
        for (int k = 0; k < 4; ++k) {
#pragma unroll
            for (int p = 0; p < 4; ++p) {
                float acc = conv[k][p];
                acc = dot2(rv[0][p],     w2[k][0], acc);
                acc = dot2(rv[0][p + 1], w2[k][1], acc);
                acc = dot2(rv[0][p + 2], w2[k][2], acc);
                acc = dot2(rv[1][p],     w2[k][3], acc);
                acc = dot2(rv[1][p + 1], w2[k][4], acc);
                acc = dot2(rv[1][p + 2], w2[k][5], acc);
                acc = dot2(rv[2][p],     w2[k][6], acc);
                acc = dot2(rv[2][p + 1], w2[k][7], acc);
                acc = dot2(rv[2][p + 2], w2[k][8], acc);
                conv[k][p] = acc;
                logit[k][p] = dot2(rv[1][p + 1], a2[k], logit[k][p]);
            }
        }

        // barrier: LDS writes drained (lgkmcnt 0) but prefetch loads for
        // g+2/g+3 stay in flight -- no vmcnt drain.
        barrier_lgkm_only();
    }

    // ---- epilogue: softmax over K=4 + mixture (all f32) ----
    const float b0 = attn_b[0], b1 = attn_b[1], b2 = attn_b[2], b3 = attn_b[3];
    float4 o;
    float* op = &o.x;
#pragma unroll
    for (int p = 0; p < 4; ++p) {
        float l0 = logit[0][p] + b0;
        float l1 = logit[1][p] + b1;
        float l2 = logit[2][p] + b2;
        float l3 = logit[3][p] + b3;
        float m = fmaxf(fmaxf(l0, l1), fmaxf(l2, l3));
        float e0 = __expf(l0 - m), e1 = __expf(l1 - m);
        float e2 = __expf(l2 - m), e3 = __expf(l3 - m);
        float s = e0 + e1 + e2 + e3;
        float num = conv[0][p] * e0 + conv[1][p] * e1
                  + conv[2][p] * e2 + conv[3][p] * e3;
        op[p] = num / s;
    }
    size_t oidx = (size_t)b * PLANE + (size_t)(h0 + r) * WW + (w0 + wb);
    *reinterpret_cast<float4*>(out + oidx) = o;
}

extern "C" void kernel_launch(void* const* d_in, const int* in_sizes, int n_in,
                              void* d_out, int out_size, void* d_ws, size_t ws_size,
                              hipStream_t stream) {
    const float* x      = (const float*)d_in[0];
    const float* weight = (const float*)d_in[1];
    const float* attn_w = (const float*)d_in[2];
    const float* attn_b = (const float*)d_in[3];
    float* out = (float*)d_out;
    uint*  wsu = (uint*)d_ws;

    kwdc_pack<<<dim3(5), 256, 0, stream>>>(weight, attn_w, wsu);
    kwdc_main<<<dim3(1024), 256, 0, stream>>>(x, wsu, attn_b, out);
}